// Round 9
// baseline (282.815 us; speedup 1.0000x reference)
//
#include <hip/hip_runtime.h>

#define BATCH 8192
#define MDIM 128
#define NL 10
#define LSTEPS 97
#define RSTEPS 96
#define NSTEPS 193   // LSTEPS + RSTEPS
#define DIM 196
#define POSL 98

typedef _Float16 half8 __attribute__((ext_vector_type(8)));
typedef float float16v __attribute__((ext_vector_type(16)));

// lgkm-only barrier: orders LDS ops; never drains vmcnt.
#define BARRIER_LGKM() asm volatile("s_waitcnt lgkmcnt(0)\ns_barrier" ::: "memory")

#define MFMA16 __builtin_amdgcn_mfma_f32_32x32x16_f16

// ---------------------------------------------------------------------------
// Transpose x into xT[pos][batch] (float2).
// ---------------------------------------------------------------------------
__global__ __launch_bounds__(256) void transpose_x(const float* __restrict__ x,
                                                   float2* __restrict__ xT) {
    __shared__ float tx[64][65];
    __shared__ float ty[64][65];
    int p0 = blockIdx.x * 32;
    int b0 = blockIdx.y * 64;
    int tid = threadIdx.x;

    int r = tid >> 2, q = tid & 3;
    const float* src = x + ((size_t)(b0 + r) * DIM + p0 + q * 8) * 2;
#pragma unroll
    for (int j = 0; j < 8; ++j) {
        int pp = q * 8 + j;
        if (p0 + pp < DIM) {
            float2 v = *(const float2*)(src + j * 2);
            tx[r][pp] = v.x;
            ty[r][pp] = v.y;
        }
    }
    __syncthreads();

    int pr = tid >> 3, cb = (tid & 7) * 8;
    if (p0 + pr < DIM) {
        float2* dst = xT + (size_t)(p0 + pr) * BATCH + b0 + cb;
#pragma unroll
        for (int j = 0; j < 8; ++j) {
            float2 v;
            v.x = tx[cb + j][pr];
            v.y = ty[cb + j][pr];
            dst[j] = v;
        }
    }
}

// ---------------------------------------------------------------------------
// pack_w96: frag-pack ONLY the left tail step (g=96) weights (old pack_w left
// branch). 4 blocks (one per n-tile).
// ---------------------------------------------------------------------------
__global__ __launch_bounds__(256) void pack_w96(const float* __restrict__ w_left,
                                                _Float16* __restrict__ pwt) {
    int nt = blockIdx.x;               // 0..3
    int tid = threadIdx.x;
    int l = tid & 63;
    int kq = tid >> 6;
    int hi = l >> 5;
    int n = nt * 32 + (l & 31);
    const float* base = w_left + (size_t)96 * 2 * MDIM * MDIM;
#pragma unroll
    for (int p = 0; p < 4; ++p) {
        int kt = p * 4 + kq;
        int k0 = kt * 16 + hi * 8;
        half8 hv;
#pragma unroll
        for (int j = 0; j < 8; ++j)
            hv[j] = (_Float16)base[(size_t)(k0 + j) * MDIM + n];
        *(half8*)(pwt + ((size_t)nt * 16 + kt) * 512 + l * 8) = hv;
    }
}

// ---------------------------------------------------------------------------
// pack_wpair: precompute fused 2-step weight products
//   P_ij = W^i_{g0} @ W^j_{g1}   (128x128 f16, in A-frag layout)
// using the scalar-commute identity  C'' = sum_ij (x_g0.i * x_g1.j) (.) (C P_ij).
// grid = 96 pairs x 4 (ij); block = 256 thr (4 waves = n-tiles).
// Layout conventions identical to the (verified) chain kernel:
//   A-frag: lane<->n, reg<->k;  B-frag: lane<->col, reg<->k;
//   D: col = lane&31 (B's lane dim), reg r -> row (A's lane dim) via
//   rmap(r,hi) = (r&3) + 8*(r>>2) + 4*hi.
// Here: A = W^j_{g1} (lane<->n, k=q), B[q][m] = W^i_{g0}[m][q] (lane<->m)
//   => D[reg<->n][lane<->m] = P_ij[m][n].  Transposed to A-frag order via LDS.
// ---------------------------------------------------------------------------
__global__ __launch_bounds__(256) void pack_wpair(const float* __restrict__ wl,
                                                  const float* __restrict__ wr,
                                                  _Float16* __restrict__ wp) {
    __shared__ _Float16 P[128][130];     // padded: conflict-free column writes
    int blk = blockIdx.x;                // pair*4 + ij
    int pair = blk >> 2;                 // 0..95 (0..47 left, 48..95 right)
    int ij = blk & 3;
    int i = ij >> 1, j = ij & 1;
    bool left = pair < 48;
    int sp = left ? pair : pair - 48;
    int tid = threadIdx.x;
    int l = tid & 63, nt = tid >> 6, bl = l & 31, hi = l >> 5;

    // ---- A-frags: af[kt][jj] = W^j_{g1}[q][n], q=kt*16+hi*8+jj, n=nt*32+bl
    half8 af[8];
    if (left) {
        // W^j_{g1}[q][n] = wl[((2sp+1)*2 + j)*128 + q][n]
        const float* base = wl + (((size_t)(2 * sp + 1) * 2 + j) * 128) * 128;
#pragma unroll
        for (int kt = 0; kt < 8; ++kt) {
            int q0 = kt * 16 + hi * 8;
#pragma unroll
            for (int jj = 0; jj < 8; ++jj)
                af[kt][jj] = (_Float16)base[(size_t)(q0 + jj) * 128 + nt * 32 + bl];
        }
    } else {
        // g1 = 97 + (2sp+1): W^j[q][n] = wr[(95-t1)*2 + j][n][q]  (contig in q)
        int t1 = 2 * sp + 1;
        const float* row = wr + ((((size_t)(95 - t1) * 2 + j) * 128)
                               + nt * 32 + bl) * 128;
#pragma unroll
        for (int kt = 0; kt < 8; ++kt) {
            int q0 = kt * 16 + hi * 8;
            float4 v0 = *(const float4*)(row + q0);
            float4 v1 = *(const float4*)(row + q0 + 4);
            af[kt][0] = (_Float16)v0.x; af[kt][1] = (_Float16)v0.y;
            af[kt][2] = (_Float16)v0.z; af[kt][3] = (_Float16)v0.w;
            af[kt][4] = (_Float16)v1.x; af[kt][5] = (_Float16)v1.y;
            af[kt][6] = (_Float16)v1.z; af[kt][7] = (_Float16)v1.w;
        }
    }

    // ---- per m-tile: B-frags, 8-chain MFMA, write D into P_lds
#pragma unroll 1
    for (int mt = 0; mt < 4; ++mt) {
        half8 bf[8];
        if (left) {
            // B[q][m] = W^i_{g0}[m][q] = wl[(2sp*2 + i)*128 + m][q] (contig q)
            const float* row = wl + ((((size_t)(2 * sp) * 2 + i) * 128)
                                   + mt * 32 + bl) * 128;
#pragma unroll
            for (int kt = 0; kt < 8; ++kt) {
                int q0 = kt * 16 + hi * 8;
                float4 v0 = *(const float4*)(row + q0);
                float4 v1 = *(const float4*)(row + q0 + 4);
                bf[kt][0] = (_Float16)v0.x; bf[kt][1] = (_Float16)v0.y;
                bf[kt][2] = (_Float16)v0.z; bf[kt][3] = (_Float16)v0.w;
                bf[kt][4] = (_Float16)v1.x; bf[kt][5] = (_Float16)v1.y;
                bf[kt][6] = (_Float16)v1.z; bf[kt][7] = (_Float16)v1.w;
            }
        } else {
            // W^i_{g0}[m][q] = wr[(95-t0)*2 + i][q][m]  (strided in q)
            int t0 = 2 * sp;
            const float* base = wr + (((size_t)(95 - t0) * 2 + i) * 128) * 128;
#pragma unroll
            for (int kt = 0; kt < 8; ++kt) {
                int q0 = kt * 16 + hi * 8;
#pragma unroll
                for (int jj = 0; jj < 8; ++jj)
                    bf[kt][jj] = (_Float16)base[(size_t)(q0 + jj) * 128
                                              + mt * 32 + bl];
            }
        }
        float16v d = {};
#pragma unroll
        for (int kt = 0; kt < 8; ++kt)
            d = MFMA16(af[kt], bf[kt], d, 0, 0, 0);
        // lane holds D[n = nt*32+rmap(r,hi)][m = mt*32+bl]  ->  P[m][n]
#pragma unroll
        for (int r = 0; r < 16; ++r)
            P[mt * 32 + bl][nt * 32 + (r & 3) + 8 * (r >> 2) + 4 * hi]
                = (_Float16)d[r];
    }
    __syncthreads();

    // ---- read back in chain-A-frag layout (lane<->n, reg<->m) and store
    _Float16* dst = wp + ((size_t)pair * 128 + ij * 32 + nt * 8) * 512
                  + (size_t)l * 8;
#pragma unroll
    for (int kt2 = 0; kt2 < 8; ++kt2) {
        int m0 = kt2 * 16 + hi * 8;
        half8 hv;
#pragma unroll
        for (int jj = 0; jj < 8; ++jj)
            hv[jj] = P[m0 + jj][nt * 32 + bl];
        *(half8*)(dst + (size_t)kt2 * 512) = hv;
    }
}

// ---------------------------------------------------------------------------
// Pack w_label into f16 A-frag order (unchanged).
// ---------------------------------------------------------------------------
__global__ __launch_bounds__(256) void pack_label(const float* __restrict__ w_label,
                                                  _Float16* __restrict__ gp) {
    int ct = blockIdx.x;               // 0..39
    int tid = threadIdx.x;
    int l = tid & 63;
    int kq = tid >> 6;
    int hi = l >> 5;
    int outcol = ct * 32 + (l & 31);
    int n = outcol & 127;
    int lab = outcol >> 7;
#pragma unroll
    for (int p2 = 0; p2 < 4; ++p2) {
        int kt = p2 * 4 + kq;
        int k0 = kt * 16 + hi * 8;
        int p = k0 >> 7;
        int m0 = k0 & 127;
        half8 hv;
#pragma unroll
        for (int j = 0; j < 8; ++j)
            hv[j] = (_Float16)w_label[(((size_t)p * MDIM + m0 + j) * MDIM + n) * NL + lab];
        *(half8*)(gp + (size_t)(ct * 16 + kt) * 512 + l * 8) = hv;
    }
}

// ---------------------------------------------------------------------------
// FUSED chain kernel: 48 pairs (2 old steps each) + left tail step.
// R7 probe: step = A-stream(1380cy) + core(2324cy), additive & schedule-
// invariant across 6 structures. Fusion keeps A-bytes & MFMA constant but
// HALVES the carry LDS round-trip, barriers, cvt+ds_write per old-step.
// ---------------------------------------------------------------------------

#define READ_BF_F(SRC, ROWOFF)                                               \
    half8 bf[8];                                                             \
    _Pragma("unroll")                                                        \
    for (int q = 0; q < 8; ++q) {                                            \
        int nb = q * 2 + hi;                                                 \
        int phys = nb ^ (bl & 15);                                           \
        bf[q] = *(const half8*)&cbuf[SRC][(bl + ROWOFF) * 128 + phys * 8];   \
    }

#define PROD_CHAINS()                                                        \
    float16v p0 = {}, p1 = {}, p2 = {}, p3 = {};                             \
    _Pragma("unroll")                                                        \
    for (int kt = 0; kt < 8; ++kt) {                                         \
        p0 = MFMA16(A[kt],      bf[kt], p0, 0, 0, 0);                        \
        p1 = MFMA16(A[kt + 8],  bf[kt], p1, 0, 0, 0);                        \
        p2 = MFMA16(A[kt + 16], bf[kt], p2, 0, 0, 0);                        \
        p3 = MFMA16(A[kt + 24], bf[kt], p3, 0, 0, 0);                        \
    }

#define EPI4(DST, ROWOFF, C00, C01, C10, C11)                                \
    _Pragma("unroll")                                                        \
    for (int rq = 0; rq < 4; ++rq) {                                         \
        int nb = nt * 4 + rq;                                                \
        int phys = nb ^ (bl & 15);                                           \
        union { _Float16 h[4]; uint2 u; } t;                                 \
        _Pragma("unroll")                                                    \
        for (int r = 0; r < 4; ++r) {                                        \
            int rr = rq * 4 + r;                                             \
            t.h[r] = (_Float16)((C00) * p0[rr] + (C01) * p1[rr]              \
                              + (C10) * p2[rr] + (C11) * p3[rr]);            \
        }                                                                    \
        *(uint2*)&cbuf[DST][(bl + ROWOFF) * 128 + phys * 8 + hi * 4] = t.u;  \
    }

#define FINAL4(ROWOFF, C00, C01, C10, C11)                                   \
    _Pragma("unroll")                                                        \
    for (int r = 0; r < 16; ++r) {                                           \
        int n = nt * 32 + (r & 3) + 8 * (r >> 2) + 4 * hi;                   \
        outT[(size_t)n * BATCH + bbase + (ROWOFF) + bl] =                    \
            (C00) * p0[r] + (C01) * p1[r] + (C10) * p2[r] + (C11) * p3[r];   \
    }

// old single-step macros for the left tail
#define CHAIN_MFMA_BLOCK(AF, SRC)                                            \
    half8 bf0[8], bf1[8];                                                    \
    _Pragma("unroll")                                                        \
    for (int q = 0; q < 8; ++q) {                                            \
        int nb = q * 2 + hi;                                                 \
        int phys = nb ^ (bl & 15);                                           \
        bf0[q] = *(const half8*)&cbuf[SRC][bl * 128 + phys * 8];             \
        bf1[q] = *(const half8*)&cbuf[SRC][(bl + 32) * 128 + phys * 8];      \
    }                                                                        \
    float16v a00 = {}, a01 = {}, a10 = {}, a11 = {};                         \
    _Pragma("unroll")                                                        \
    for (int kt = 0; kt < 8; ++kt) {                                         \
        a00 = MFMA16(AF[kt], bf0[kt], a00, 0, 0, 0);                         \
        a10 = MFMA16(AF[kt], bf1[kt], a10, 0, 0, 0);                         \
        a01 = MFMA16(AF[kt + 8], bf0[kt], a01, 0, 0, 0);                     \
        a11 = MFMA16(AF[kt + 8], bf1[kt], a11, 0, 0, 0);                     \
    }

#define FINAL_STORE()                                                        \
    _Pragma("unroll")                                                        \
    for (int r = 0; r < 16; ++r) {                                           \
        int n = nt * 32 + (r & 3) + 8 * (r >> 2) + 4 * hi;                   \
        outT[(size_t)n * BATCH + bbase + bl] = xc0.x * a00[r] + xc0.y * a01[r]; \
        outT[(size_t)n * BATCH + bbase + 32 + bl] = xc1.x * a10[r] + xc1.y * a11[r]; \
    }

__global__ __launch_bounds__(256, 1) void chain_fused(
        const float2* __restrict__ xT, const float* __restrict__ w0,
        const float* __restrict__ w_end, const _Float16* __restrict__ wp,
        const _Float16* __restrict__ pwt,
        float* __restrict__ leftT, float* __restrict__ rightT) {
    __shared__ _Float16 cbuf[2][64 * 128];   // 2 x 16 KB carry

    int bid = blockIdx.x;
    bool is_left = bid < 128;
    int bbase = (is_left ? bid : bid - 128) * 64;
    int tid = threadIdx.x;
    int l = tid & 63;
    int nt = tid >> 6;        // wave = n-tile
    int bl = l & 31;
    int hi = l >> 5;

    float* outT = is_left ? leftT : rightT;

    // --- initial carry into cbuf[0]
    {
        const float* wst = is_left ? w0 : w_end;
        int pos0 = is_left ? 0 : (DIM - 1);
        int b = tid >> 2;                        // 0..63
        const float2 xv0 = xT[(size_t)pos0 * BATCH + bbase + b];
#pragma unroll
        for (int h = 0; h < 4; ++h) {
            int nb = (tid & 3) * 4 + h;          // 0..15
            half8 hv;
#pragma unroll
            for (int j = 0; j < 8; ++j) {
                int n = nb * 8 + j;
                hv[j] = (_Float16)(xv0.x * wst[n] + xv0.y * wst[MDIM + n]);
            }
            int phys = nb ^ (b & 15);
            *(half8*)&cbuf[0][b * 128 + phys * 8] = hv;
        }
    }

    // per-wave wpair base: pair sp at +sp*128KB; frag (ij,kt) at +ij*32KB+kt*1KB
    const char* wpb = (const char*)wp
                    + ((size_t)(is_left ? 0 : 48) * 131072)
                    + (size_t)nt * 8192 + (size_t)l * 16;
    const float2* xTb = xT + bbase;

    __syncthreads();   // carry init visible

#pragma unroll 1
    for (int sp2 = 0; sp2 < 48; ++sp2) {
        int src = sp2 & 1;
        // x positions: pair fuses old steps (2sp2, 2sp2+1)
        int pA = is_left ? (1 + 2 * sp2) : (194 - 2 * sp2);
        int pB = is_left ? (2 + 2 * sp2) : (193 - 2 * sp2);
        float2 xa0 = xTb[(size_t)pA * BATCH + bl];
        float2 xb0 = xTb[(size_t)pB * BATCH + bl];
        float2 xa1 = xTb[(size_t)pA * BATCH + 32 + bl];
        float2 xb1 = xTb[(size_t)pB * BATCH + 32 + bl];

        const char* pp = wpb + (size_t)sp2 * 131072;
        half8 A[32];
#pragma unroll
        for (int f = 0; f < 32; ++f)
            A[f] = *(const half8*)(pp + (size_t)(f >> 3) * 32768
                                      + (size_t)(f & 7) * 1024);

        bool fin = (!is_left) && (sp2 == 47);
        {   // row group 0
            READ_BF_F(src, 0)
            PROD_CHAINS()
            float c00 = xa0.x * xb0.x, c01 = xa0.x * xb0.y;
            float c10 = xa0.y * xb0.x, c11 = xa0.y * xb0.y;
            if (fin) { FINAL4(0, c00, c01, c10, c11) }
            else     { EPI4(src ^ 1, 0, c00, c01, c10, c11) }
        }
        {   // row group 1
            READ_BF_F(src, 32)
            PROD_CHAINS()
            float c00 = xa1.x * xb1.x, c01 = xa1.x * xb1.y;
            float c10 = xa1.y * xb1.x, c11 = xa1.y * xb1.y;
            if (fin) { FINAL4(32, c00, c01, c10, c11) }
            else     { EPI4(src ^ 1, 32, c00, c01, c10, c11) }
        }
        if (!fin) BARRIER_LGKM();
    }

    if (is_left) {   // tail step 96 (position 97), carry in cbuf[0]
        const char* pt = (const char*)pwt + (size_t)(nt * 16) * 1024
                       + (size_t)l * 16;
        half8 A0[16];
#pragma unroll
        for (int kt = 0; kt < 16; ++kt)
            A0[kt] = *(const half8*)(pt + kt * 1024);
        float2 xc0 = xTb[(size_t)97 * BATCH + bl];
        float2 xc1 = xTb[(size_t)97 * BATCH + 32 + bl];
        CHAIN_MFMA_BLOCK(A0, 0)
        FINAL_STORE()
    }
}

// ---------------------------------------------------------------------------
// Label contraction via MFMA (unchanged).
// ---------------------------------------------------------------------------
__global__ __launch_bounds__(256, 2) void label_mfma(
        const float2* __restrict__ xT, const _Float16* __restrict__ gp,
        const float* __restrict__ leftT, const float* __restrict__ rightT,
        float* __restrict__ out) {
    __shared__ _Float16 R[32 * 256];     // 16 KB
    __shared__ float pl[4][32][5];
    __shared__ float xl_s[32][2];

    int bx = blockIdx.x;                 // 0/1 -> labels [bx*5, +5)
    int bbase = blockIdx.y * 32;
    int tid = threadIdx.x;
    int l = tid & 63, nt = tid >> 6, bl = l & 31, hi = l >> 5;

    if (tid < 32) {
        const float2 v = xT[(size_t)POSL * BATCH + bbase + tid];
        xl_s[tid][0] = v.x; xl_s[tid][1] = v.y;
    }
    __syncthreads();

#pragma unroll
    for (int q = 0; q < 4; ++q) {
        int id = tid + q * 256;          // 0..1023
        int m = id >> 3;
        int b4 = (id & 7) * 4;
        float4 v = *(const float4*)&leftT[(size_t)m * BATCH + bbase + b4];
        float vv[4] = {v.x, v.y, v.z, v.w};
#pragma unroll
        for (int bi = 0; bi < 4; ++bi) {
            int b = b4 + bi;
            int kb0 = m >> 3;
            int ph0 = (kb0 & 16) | ((kb0 ^ b) & 15);
            R[b * 256 + ph0 * 8 + (m & 7)] = (_Float16)(xl_s[b][0] * vv[bi]);
            int kb1 = kb0 + 16;
            int ph1 = (kb1 & 16) | ((kb1 ^ b) & 15);
            R[b * 256 + ph1 * 8 + (m & 7)] = (_Float16)(xl_s[b][1] * vv[bi]);
        }
    }

    float rv[16];
#pragma unroll
    for (int r = 0; r < 16; ++r) {
        int n = nt * 32 + (r & 3) + 8 * (r >> 2) + 4 * hi;
        rv[r] = rightT[(size_t)n * BATCH + bbase + bl];
    }
    __syncthreads();

    half8 rf[16];
#pragma unroll
    for (int kt = 0; kt < 16; ++kt) {
        int kb = kt * 2 + hi;
        int ph = (kb & 16) | ((kb ^ bl) & 15);
        rf[kt] = *(const half8*)&R[bl * 256 + ph * 8];
    }

    int l0 = bx * 5;
    float outv[5];
#pragma unroll
    for (int li = 0; li < 5; ++li) {
        int ct = (l0 + li) * 4 + nt;
        float16v acc = {};
#pragma unroll
        for (int kt = 0; kt < 16; ++kt) {
            half8 a = *(const half8*)(gp + (size_t)(ct * 16 + kt) * 512 + l * 8);
            acc = __builtin_amdgcn_mfma_f32_32x32x16_f16(a, rf[kt], acc, 0, 0, 0);
        }
        float p = 0.f;
#pragma unroll
        for (int r = 0; r < 16; ++r) p += acc[r] * rv[r];
        p += __shfl_xor(p, 32, 64);
        outv[li] = p;
    }
    if (hi == 0) {
#pragma unroll
        for (int li = 0; li < 5; ++li) pl[nt][bl][li] = outv[li];
    }
    __syncthreads();
    if (tid < 160) {
        int b = tid / 5, li = tid % 5;
        out[(size_t)(bbase + b) * NL + l0 + li] =
            pl[0][b][li] + pl[1][b][li] + pl[2][b][li] + pl[3][b][li];
    }
}

// ---------------------------------------------------------------------------
extern "C" void kernel_launch(void* const* d_in, const int* in_sizes, int n_in,
                              void* d_out, int out_size, void* d_ws, size_t ws_size,
                              hipStream_t stream) {
    const float* x       = (const float*)d_in[0];
    const float* w0      = (const float*)d_in[1];
    const float* w_left  = (const float*)d_in[2];
    const float* w_label = (const float*)d_in[3];
    const float* w_right = (const float*)d_in[4];
    const float* w_end   = (const float*)d_in[5];

    _Float16* wp  = (_Float16*)d_ws;                      // 96 pairs x 128KB = 12.58MB
    _Float16* pwt = wp + (size_t)96 * 65536;              // left tail frags, 64KB
    _Float16* gp  = pwt + 32768;                          // label frags, 0.66MB
    float* leftT  = (float*)(gp + (size_t)40 * 16 * 512); // 4MB
    float* rightT = leftT + (size_t)MDIM * BATCH;         // 4MB
    float2* xT    = (float2*)(rightT + (size_t)MDIM * BATCH); // 12.85MB

    transpose_x<<<dim3((DIM + 31) / 32, BATCH / 64), 256, 0, stream>>>(x, xT);
    pack_w96<<<dim3(4), 256, 0, stream>>>(w_left, pwt);
    pack_wpair<<<dim3(96 * 4), 256, 0, stream>>>(w_left, w_right, wp);
    pack_label<<<dim3(40), 256, 0, stream>>>(w_label, gp);
    chain_fused<<<dim3(256), 256, 0, stream>>>(xT, w0, w_end, wp, pwt,
                                               leftT, rightT);
    label_mfma<<<dim3(2, BATCH / 32), 256, 0, stream>>>(xT, gp, leftT, rightT,
                                                        (float*)d_out);
}